// Round 5
// baseline (139.119 us; speedup 1.0000x reference)
//
#include <hip/hip_runtime.h>
#include <hip/hip_bf16.h>

// Problem constants (fixed by setup_inputs)
#define BATCH 32
#define LSEQ 1025
#define TT 2048
#define NTOK 513      // 1 + (LSEQ-1)/2
#define EMB 384
#define FT 32         // frames per tile (block)
#define WMAX 64       // per-chunk token capacity (chunk loop handles overflow)
#define INV_SQRT_2PI 0.3989422804014327f

// ---------------------------------------------------------------------------
// Inclusive Hillis-Steele scan over NTOK elements with 256 threads.
// ---------------------------------------------------------------------------
__device__ inline float* scan513(float* src, float* dst) {
  for (int off = 1; off < NTOK; off <<= 1) {
    for (int i = threadIdx.x; i < NTOK; i += 256) {
      float v = src[i];
      if (i >= off) v += src[i - off];
      dst[i] = v;
    }
    __syncthreads();
    float* t = src; src = dst; dst = t;
  }
  return src;
}

// ---------------------------------------------------------------------------
// prep: merge blank/token pairs, parallel cumsum, filter tokens that can ever
// have nonzero weight (d>=1 && tok!=PAD; d=0 underflows exactly: centers are
// int/half-int, frame midpoints x.5 -> |z|>=5e5), ordered compaction into
// 8-byte records {c, (d<<17)|tok*EMB}. Also per-batch kept count and total.
// ---------------------------------------------------------------------------
__global__ __launch_bounds__(256) void prep_kernel(
    const int* __restrict__ text, const int* __restrict__ durs,
    float2* __restrict__ kept, int* __restrict__ counts,
    float* __restrict__ totals) {
  const int b = blockIdx.x;
  const int tid = threadIdx.x;
  __shared__ float s_a[NTOK], s_b[NTOK];
  __shared__ float s_c[NTOK];
  __shared__ float s_d[NTOK];
  __shared__ int s_tok[NTOK];

  const int* tb = text + b * LSEQ;
  const int* db = durs + b * LSEQ;
  for (int n = tid; n < NTOK; n += 256) {
    int dm, tk;
    if (n == 0) { dm = db[0]; tk = tb[0]; }
    else { dm = db[2 * n - 1] + db[2 * n]; tk = tb[2 * n - 1]; }
    s_d[n] = (float)dm;
    s_a[n] = (float)dm;
    s_tok[n] = tk;
  }
  __syncthreads();
  float* cum = scan513(s_a, s_b);          // exact: small ints
  for (int n = tid; n < NTOK; n += 256) {
    s_c[n] = cum[n] - 0.5f * s_d[n];
  }
  if (tid == 0) totals[b] = cum[NTOK - 1];
  __syncthreads();
  float* flagbuf = (cum == s_a) ? s_a : s_b;
  float* other = (cum == s_a) ? s_b : s_a;
  for (int n = tid; n < NTOK; n += 256) {
    flagbuf[n] = (s_d[n] >= 1.0f && s_tok[n] != 0) ? 1.0f : 0.0f;
  }
  __syncthreads();
  float* incl = scan513(flagbuf, other);
  for (int n = tid; n < NTOK; n += 256) {
    float d = s_d[n];
    int tk = s_tok[n];
    if (d >= 1.0f && tk != 0) {
      int pos = (int)incl[n] - 1;
      int packed = ((int)d << 17) | (tk * EMB);
      kept[b * NTOK + pos] = make_float2(s_c[n], __int_as_float(packed));
    }
  }
  if (tid == 0) counts[b] = (int)incl[NTOK - 1];
}

// ---------------------------------------------------------------------------
// frames: one block per (batch, 32-frame tile), 384 threads (6 waves).
// Chunk loop over <=64 window candidates at a time:
//   - wave 0 ballot-compacts tokens whose support touches the tile (no
//     atomics, no reset barrier); typical cnt ~ 22
//   - eval dense s_w[cnt][32] (one exp per pair, spread over 384 threads)
//   - tid<32 accumulates per-frame sums while all threads run the BRANCH-FREE
//     mix: thread = (frame-octet g=tid/96, col-quad q=tid%96); per token:
//     2 broadcast ds_read_b128 (8 weights) + 1 coalesced float4 emb load +
//     32 FMAs (16 FMA per LDS instr — 2x round 4)
// Epilogue: factor = valid/(sum+eps), 8 float4 stores per thread.
// ---------------------------------------------------------------------------
__global__ __launch_bounds__(384) void frames_kernel(
    const float2* __restrict__ kept, const int* __restrict__ counts,
    const float* __restrict__ totals, const float* __restrict__ emb,
    float* __restrict__ out) {
  const int t0 = blockIdx.x * FT;
  const int b = blockIdx.y;
  const int tid = threadIdx.x;
  const int g = tid / 96;        // frame-octet 0..3
  const int q = tid % 96;        // col-quad 0..95
  const int fbase = g * 8;

  __shared__ float4 s_tk[WMAX];      // {c, inv_sig, coef, off bitcast}
  __shared__ float s_w[WMAX][FT];
  __shared__ float s_sum[FT];
  __shared__ int s_cnt;

  const int M = counts[b];
  const float total = totals[b];
  const float2* kb = kept + b * NTOK;

  const float tileLo = (float)t0 + 0.5f;
  const float tileHi = (float)t0 + 31.5f;
  const bool tile_valid = tileLo < total;

  // candidate window: centers in [t0-40.5, t0+72.5] (max reach 6.7*6=40.2)
  int lo = 0, hi = 0;
  if (tile_valid) {
    const float loB = (float)t0 - 40.5f;
    const float hiB = (float)t0 + 72.5f;
    int l = 0, r = M;
    while (l < r) { int m = (l + r) >> 1; if (kb[m].x < loB) l = m + 1; else r = m; }
    lo = l;
    r = M;
    while (l < r) { int m = (l + r) >> 1; if (kb[m].x <= hiB) l = m + 1; else r = m; }
    hi = l;
  }

  if (tid < FT) s_sum[tid] = 0.f;

  float4 acc[8];
#pragma unroll
  for (int k = 0; k < 8; ++k) acc[k] = make_float4(0.f, 0.f, 0.f, 0.f);

  const float t0f = (float)t0 + 0.5f;

  for (int pos = lo; pos < hi; pos += WMAX) {
    const int cand = min(hi - pos, WMAX);
    __syncthreads();  // s_sum init / prev chunk's s_tk,s_w consumers done
    if (tid < 64) {   // wave 0 only: ballot compaction (order-free for sums)
      bool touch = false;
      float cc = 0.f, df = 0.f;
      int packed = 0;
      if (tid < cand) {
        float2 kv = kb[pos + tid];
        cc = kv.x;
        packed = __float_as_int(kv.y);
        df = (float)(packed >> 17);
        const float reach = 6.7f * df + 1e-4f;     // covers fp32-exp support
        touch = (cc + reach >= tileLo) && (cc - reach <= tileHi);
      }
      const unsigned long long mask = __ballot(touch);
      if (touch) {
        const int slot = __popcll(mask & ((1ull << (tid & 63)) - 1));
        const float inv_sig = 1.0f / (0.5f * df + 1e-6f);  // == ref sig
        s_tk[slot] = make_float4(cc, inv_sig, INV_SQRT_2PI * inv_sig,
                                 __int_as_float(packed & 0x1FFFF));
      }
      if (tid == 0) s_cnt = __popcll(mask);
    }
    __syncthreads();
    const int cnt = s_cnt;

    // dense weight eval: one mul + one exp per (token, frame)
    const int pairs = cnt * FT;
    for (int idx = tid; idx < pairs; idx += 384) {
      const int n = idx >> 5, f = idx & (FT - 1);
      const float4 tk = s_tk[n];
      const float z = (t0f + (float)f - tk.x) * tk.y;
      s_w[n][f] = tk.z * __expf(-0.5f * z * z);
    }
    __syncthreads();

    // per-frame sum accumulation (wave 0 low half) runs alongside the mix
    if (tid < FT) {
      float s = 0.f;
      for (int n = 0; n < cnt; ++n) s += s_w[n][tid];
      s_sum[tid] += s;
    }

    // branch-free mix
    for (int n = 0; n < cnt; ++n) {
      const float4 tk = s_tk[n];
      const float4 v = *(const float4*)(emb + __float_as_int(tk.w) + q * 4);
      const float4 w0 = *(const float4*)&s_w[n][fbase];      // broadcast b128
      const float4 w1 = *(const float4*)&s_w[n][fbase + 4];  // broadcast b128
      acc[0].x += w0.x * v.x; acc[0].y += w0.x * v.y;
      acc[0].z += w0.x * v.z; acc[0].w += w0.x * v.w;
      acc[1].x += w0.y * v.x; acc[1].y += w0.y * v.y;
      acc[1].z += w0.y * v.z; acc[1].w += w0.y * v.w;
      acc[2].x += w0.z * v.x; acc[2].y += w0.z * v.y;
      acc[2].z += w0.z * v.z; acc[2].w += w0.z * v.w;
      acc[3].x += w0.w * v.x; acc[3].y += w0.w * v.y;
      acc[3].z += w0.w * v.z; acc[3].w += w0.w * v.w;
      acc[4].x += w1.x * v.x; acc[4].y += w1.x * v.y;
      acc[4].z += w1.x * v.z; acc[4].w += w1.x * v.w;
      acc[5].x += w1.y * v.x; acc[5].y += w1.y * v.y;
      acc[5].z += w1.y * v.z; acc[5].w += w1.y * v.w;
      acc[6].x += w1.z * v.x; acc[6].y += w1.z * v.y;
      acc[6].z += w1.z * v.z; acc[6].w += w1.z * v.w;
      acc[7].x += w1.w * v.x; acc[7].y += w1.w * v.y;
      acc[7].z += w1.w * v.z; acc[7].w += w1.w * v.w;
    }
  }
  __syncthreads();  // s_sum final

  // epilogue: normalize + write (invalid frames -> exact zeros)
  float* obase = out + ((size_t)b * TT + t0 + fbase) * EMB + q * 4;
#pragma unroll
  for (int k = 0; k < 8; ++k) {
    const float tf = t0f + (float)(fbase + k);
    const float fac = (tf < total) ? 1.0f / (s_sum[fbase + k] + 1e-6f) : 0.0f;
    *(float4*)(obase + (size_t)k * EMB) =
        make_float4(acc[k].x * fac, acc[k].y * fac,
                    acc[k].z * fac, acc[k].w * fac);
  }
}

extern "C" void kernel_launch(void* const* d_in, const int* in_sizes, int n_in,
                              void* d_out, int out_size, void* d_ws,
                              size_t ws_size, hipStream_t stream) {
  const int* text = (const int*)d_in[0];
  const int* durs = (const int*)d_in[1];
  const float* emb = (const float*)d_in[2];
  float* out = (float*)d_out;

  // workspace: kept float2[32*513] (131 KB) | counts int[32] | totals float[32]
  float2* kept = (float2*)d_ws;
  int* counts = (int*)(kept + BATCH * NTOK);
  float* totals = (float*)(counts + BATCH);

  prep_kernel<<<BATCH, 256, 0, stream>>>(text, durs, kept, counts, totals);
  frames_kernel<<<dim3(TT / FT, BATCH), 384, 0, stream>>>(kept, counts, totals,
                                                          emb, out);
}

// Round 6
// 133.679 us; speedup vs baseline: 1.0407x; 1.0407x over previous
//
#include <hip/hip_runtime.h>
#include <hip/hip_bf16.h>

// Problem constants (fixed by setup_inputs)
#define BATCH 32
#define LSEQ 1025
#define TT 2048
#define NTOK 513      // 1 + (LSEQ-1)/2
#define EMB 384
#define FT 16         // frames per tile (block)
#define WMAX 104      // window span 97 frames, kept-token spacing >=1 -> <=100
#define INV_SQRT_2PI 0.3989422804014327f

// ---------------------------------------------------------------------------
// Inclusive Hillis-Steele scan over NTOK elements with 256 threads.
// ---------------------------------------------------------------------------
__device__ inline float* scan513(float* src, float* dst) {
  for (int off = 1; off < NTOK; off <<= 1) {
    for (int i = threadIdx.x; i < NTOK; i += 256) {
      float v = src[i];
      if (i >= off) v += src[i - off];
      dst[i] = v;
    }
    __syncthreads();
    float* t = src; src = dst; dst = t;
  }
  return src;
}

// ---------------------------------------------------------------------------
// prep: merge blank/token pairs, parallel cumsum, filter tokens that can ever
// have nonzero weight (d>=1 && tok!=PAD; d=0 underflows exactly: centers are
// int/half-int, frame midpoints x.5 -> |z|>=5e5), ordered compaction into
// 8-byte records {c, (d<<17)|tok*EMB}. Also per-batch kept count and total.
// ---------------------------------------------------------------------------
__global__ __launch_bounds__(256) void prep_kernel(
    const int* __restrict__ text, const int* __restrict__ durs,
    float2* __restrict__ kept, int* __restrict__ counts,
    float* __restrict__ totals) {
  const int b = blockIdx.x;
  const int tid = threadIdx.x;
  __shared__ float s_a[NTOK], s_b[NTOK];
  __shared__ float s_c[NTOK];
  __shared__ float s_d[NTOK];
  __shared__ int s_tok[NTOK];

  const int* tb = text + b * LSEQ;
  const int* db = durs + b * LSEQ;
  for (int n = tid; n < NTOK; n += 256) {
    int dm, tk;
    if (n == 0) { dm = db[0]; tk = tb[0]; }
    else { dm = db[2 * n - 1] + db[2 * n]; tk = tb[2 * n - 1]; }
    s_d[n] = (float)dm;
    s_a[n] = (float)dm;
    s_tok[n] = tk;
  }
  __syncthreads();
  float* cum = scan513(s_a, s_b);          // exact: small ints
  for (int n = tid; n < NTOK; n += 256) {
    s_c[n] = cum[n] - 0.5f * s_d[n];
  }
  if (tid == 0) totals[b] = cum[NTOK - 1];
  __syncthreads();
  float* flagbuf = (cum == s_a) ? s_a : s_b;
  float* other = (cum == s_a) ? s_b : s_a;
  for (int n = tid; n < NTOK; n += 256) {
    flagbuf[n] = (s_d[n] >= 1.0f && s_tok[n] != 0) ? 1.0f : 0.0f;
  }
  __syncthreads();
  float* incl = scan513(flagbuf, other);
  for (int n = tid; n < NTOK; n += 256) {
    float d = s_d[n];
    int tk = s_tok[n];
    if (d >= 1.0f && tk != 0) {
      int pos = (int)incl[n] - 1;
      int packed = ((int)d << 17) | (tk * EMB);
      kept[b * NTOK + pos] = make_float2(s_c[n], __int_as_float(packed));
    }
  }
  if (tid == 0) counts[b] = (int)incl[NTOK - 1];
}

// ---------------------------------------------------------------------------
// frames: one block per (batch, 16-frame tile), 192 threads (3 WAVES -> ~10
// independent barrier domains per CU; phases of different blocks overlap).
// TWO barriers total:
//   stage (tid<win loads+precomputes token params)   | sync
//   eval dense s_w[win][16] (one exp per pair)       | sync
//   mix: thread = (frame-octet g=tid/96, col-quad q=tid%96). Per token:
//        s_tk b128 (broadcast, free) + 2x s_w b128 (broadcast/2-way, free)
//        + 1 coalesced float4 emb load + 32 FMA + 8 register frame-sum adds.
//   epilogue: fac from REGISTER sums (no sum phase, no 3rd barrier),
//             8 coalesced float4 stores.
// No compaction: non-touching candidates contribute exact zeros (r5 showed
// the filter wasn't buying time; this shortens the critical path).
// ---------------------------------------------------------------------------
__global__ __launch_bounds__(192) void frames_kernel(
    const float2* __restrict__ kept, const int* __restrict__ counts,
    const float* __restrict__ totals, const float* __restrict__ emb,
    float* __restrict__ out) {
  const int t0 = blockIdx.x * FT;
  const int b = blockIdx.y;
  const int tid = threadIdx.x;
  const int g = tid / 96;        // frame-octet 0..1
  const int q = tid % 96;        // col-quad 0..95
  const int fbase = g * 8;

  __shared__ float4 s_tk[WMAX];  // {c, inv_sig, coef, off bitcast}
  __shared__ float s_w[WMAX][FT];

  const int M = counts[b];
  const float total = totals[b];
  const float2* kb = kept + b * NTOK;
  const float t0f = (float)t0 + 0.5f;

  // candidate window: centers in [t0-40.5, t0+56.5] (max reach 6.7*6=40.2)
  int lo = 0, win = 0;
  if (t0f < total) {
    const float loB = (float)t0 - 40.5f;
    const float hiB = (float)t0 + 56.5f;
    int l = 0, r = M;
    while (l < r) { int m = (l + r) >> 1; if (kb[m].x < loB) l = m + 1; else r = m; }
    lo = l;
    r = M;
    while (l < r) { int m = (l + r) >> 1; if (kb[m].x <= hiB) l = m + 1; else r = m; }
    win = l - lo;
    if (win > WMAX) win = WMAX;  // unreachable: spacing>=1 -> win<=100
  }

  // stage token params (single strided pass; win <= 104)
  if (tid < win) {
    float2 kv = kb[lo + tid];
    int packed = __float_as_int(kv.y);
    float df = (float)(packed >> 17);
    float inv_sig = 1.0f / (0.5f * df + 1e-6f);   // matches ref sig exactly
    s_tk[tid] = make_float4(kv.x, inv_sig, INV_SQRT_2PI * inv_sig,
                            __int_as_float(packed & 0x1FFFF));
  }
  __syncthreads();

  // dense weight eval: one mul + one exp per (token, frame)
  const int pairs = win * FT;
  for (int idx = tid; idx < pairs; idx += 192) {
    const int n = idx >> 4, f = idx & (FT - 1);
    const float4 tk = s_tk[n];
    const float z = (t0f + (float)f - tk.x) * tk.y;
    s_w[n][f] = tk.z * __expf(-0.5f * z * z);
  }
  __syncthreads();

  // mix: branch-free over all candidates; frame-sums kept in registers
  float4 acc[8];
  float wsum[8];
#pragma unroll
  for (int k = 0; k < 8; ++k) {
    acc[k] = make_float4(0.f, 0.f, 0.f, 0.f);
    wsum[k] = 0.f;
  }

#pragma unroll 2
  for (int n = 0; n < win; ++n) {
    const float4 tk = s_tk[n];                      // broadcast b128 (free)
    const float4 v = *(const float4*)(emb + __float_as_int(tk.w) + q * 4);
    const float4 w0 = *(const float4*)&s_w[n][fbase];      // broadcast b128
    const float4 w1 = *(const float4*)&s_w[n][fbase + 4];  // broadcast b128
    wsum[0] += w0.x; wsum[1] += w0.y; wsum[2] += w0.z; wsum[3] += w0.w;
    wsum[4] += w1.x; wsum[5] += w1.y; wsum[6] += w1.z; wsum[7] += w1.w;
    acc[0].x += w0.x * v.x; acc[0].y += w0.x * v.y;
    acc[0].z += w0.x * v.z; acc[0].w += w0.x * v.w;
    acc[1].x += w0.y * v.x; acc[1].y += w0.y * v.y;
    acc[1].z += w0.y * v.z; acc[1].w += w0.y * v.w;
    acc[2].x += w0.z * v.x; acc[2].y += w0.z * v.y;
    acc[2].z += w0.z * v.z; acc[2].w += w0.z * v.w;
    acc[3].x += w0.w * v.x; acc[3].y += w0.w * v.y;
    acc[3].z += w0.w * v.z; acc[3].w += w0.w * v.w;
    acc[4].x += w1.x * v.x; acc[4].y += w1.x * v.y;
    acc[4].z += w1.x * v.z; acc[4].w += w1.x * v.w;
    acc[5].x += w1.y * v.x; acc[5].y += w1.y * v.y;
    acc[5].z += w1.y * v.z; acc[5].w += w1.y * v.w;
    acc[6].x += w1.z * v.x; acc[6].y += w1.z * v.y;
    acc[6].z += w1.z * v.z; acc[6].w += w1.z * v.w;
    acc[7].x += w1.w * v.x; acc[7].y += w1.w * v.y;
    acc[7].z += w1.w * v.z; acc[7].w += w1.w * v.w;
  }

  // epilogue: normalize from register sums + write (invalid frames -> zeros)
  float* obase = out + ((size_t)b * TT + t0 + fbase) * EMB + q * 4;
#pragma unroll
  for (int k = 0; k < 8; ++k) {
    const float tf = t0f + (float)(fbase + k);
    const float fac = (tf < total) ? 1.0f / (wsum[k] + 1e-6f) : 0.0f;
    *(float4*)(obase + (size_t)k * EMB) =
        make_float4(acc[k].x * fac, acc[k].y * fac,
                    acc[k].z * fac, acc[k].w * fac);
  }
}

extern "C" void kernel_launch(void* const* d_in, const int* in_sizes, int n_in,
                              void* d_out, int out_size, void* d_ws,
                              size_t ws_size, hipStream_t stream) {
  const int* text = (const int*)d_in[0];
  const int* durs = (const int*)d_in[1];
  const float* emb = (const float*)d_in[2];
  float* out = (float*)d_out;

  // workspace: kept float2[32*513] (131 KB) | counts int[32] | totals float[32]
  float2* kept = (float2*)d_ws;
  int* counts = (int*)(kept + BATCH * NTOK);
  float* totals = (float*)(counts + BATCH);

  prep_kernel<<<BATCH, 256, 0, stream>>>(text, durs, kept, counts, totals);
  frames_kernel<<<dim3(TT / FT, BATCH), 192, 0, stream>>>(kept, counts, totals,
                                                          emb, out);
}